// Round 2
// baseline (1109.496 us; speedup 1.0000x reference)
//
#include <hip/hip_runtime.h>

typedef short s16x8 __attribute__((ext_vector_type(8)));
typedef unsigned short u16;
typedef u16 u16x8 __attribute__((ext_vector_type(8)));
typedef u16 u16x4 __attribute__((ext_vector_type(4)));
typedef float f32x4 __attribute__((ext_vector_type(4)));

#define DEVINL __device__ __forceinline__

DEVINL u16 f2bf(float f) {
    unsigned u = __float_as_uint(f);
    u += 0x7FFFu + ((u >> 16) & 1u);
    return (u16)(u >> 16);
}
DEVINL float bf2f(u16 h) { return __uint_as_float((unsigned)h << 16); }

DEVINL void gl2lds16(const void* g, void* l) {
    __builtin_amdgcn_global_load_lds((const __attribute__((address_space(1))) void*)g,
                                     (__attribute__((address_space(3))) void*)l, 16, 0, 0);
}

// ---------------------------------------------------------------------------
// Transpose-cast: src (K,N) fp32 row-major -> dst (N,K) bf16 row-major
// ---------------------------------------------------------------------------
__global__ __launch_bounds__(256) void tcast(
    const float* __restrict__ src, u16* __restrict__ dst, const int K, const int N)
{
    __shared__ float tile[32][33];
    const long k0 = (long)blockIdx.x * 32;
    const long n0 = (long)blockIdx.y * 32;
    const int tid = threadIdx.x;
    const int r = tid >> 3, c4 = (tid & 7) * 4;
    float4 v = *(const float4*)&src[(k0 + r) * N + n0 + c4];
    tile[r][c4] = v.x; tile[r][c4 + 1] = v.y; tile[r][c4 + 2] = v.z; tile[r][c4 + 3] = v.w;
    __syncthreads();
    u16x4 ov;
    ov[0] = f2bf(tile[c4][r]);     ov[1] = f2bf(tile[c4 + 1][r]);
    ov[2] = f2bf(tile[c4 + 2][r]); ov[3] = f2bf(tile[c4 + 3][r]);
    *(u16x4*)&dst[(n0 + r) * K + k0 + c4] = ov;
}

// ---------------------------------------------------------------------------
// RMSNorm (C=2048) fp32 -> bf16
// ---------------------------------------------------------------------------
__global__ __launch_bounds__(256) void rmsnorm_cast(
    const float* __restrict__ x, const float* __restrict__ wn, u16* __restrict__ out)
{
    const int C = 2048;
    const long row = blockIdx.x;
    const int tid = threadIdx.x;
    const float4* xr = (const float4*)(x + row * C);
    float4 a = xr[tid * 2], b = xr[tid * 2 + 1];
    float ss = a.x*a.x + a.y*a.y + a.z*a.z + a.w*a.w
             + b.x*b.x + b.y*b.y + b.z*b.z + b.w*b.w;
#pragma unroll
    for (int m = 1; m < 64; m <<= 1) ss += __shfl_xor(ss, m);
    __shared__ float red[4];
    if ((tid & 63) == 0) red[tid >> 6] = ss;
    __syncthreads();
    float scale = rsqrtf((red[0] + red[1] + red[2] + red[3]) * (1.f / 2048.f) + 1e-6f);
    const float4* wr = (const float4*)wn;
    float4 wa = wr[tid * 2], wb = wr[tid * 2 + 1];
    u16x8 o;
    o[0] = f2bf(a.x * scale * wa.x); o[1] = f2bf(a.y * scale * wa.y);
    o[2] = f2bf(a.z * scale * wa.z); o[3] = f2bf(a.w * scale * wa.w);
    o[4] = f2bf(b.x * scale * wb.x); o[5] = f2bf(b.y * scale * wb.y);
    o[6] = f2bf(b.z * scale * wb.z); o[7] = f2bf(b.w * scale * wb.w);
    *(u16x8*)&out[row * C + tid * 8] = o;
}

// ---------------------------------------------------------------------------
// GEMM: A (M x K) bf16 row-major, Bt (N x K) bf16 row-major, 128x128 tile.
// MODE 0: outB = bf16(acc)
// MODE 1: outF = resid + acc   (fp32)
// ---------------------------------------------------------------------------
template <int MODE>
__global__ __launch_bounds__(256, 2) void gemm128(
    const u16* __restrict__ A, const u16* __restrict__ Bt,
    const int N, const int K,
    float* __restrict__ outF, u16* __restrict__ outB,
    const float* __restrict__ resid)
{
    __shared__ u16 As[128 * 64];
    __shared__ u16 Bs[128 * 64];
    const int tid = threadIdx.x;
    const int lane = tid & 63;
    const int w = tid >> 6;
    const int wm = w >> 1, wn = w & 1;
    const int quad = lane >> 4, l16 = lane & 15;
    const long m0 = (long)blockIdx.x * 128;
    const long n0 = (long)blockIdx.y * 128;

    const u16* ga[4]; const u16* gb[4]; char* la[4]; char* lb[4];
#pragma unroll
    for (int rr = 0; rr < 4; ++rr) {
        int idx = rr * 256 + tid;
        int r = idx >> 3, c = (idx & 7) * 8;
        ga[rr] = A + (m0 + r) * K + c;
        gb[rr] = Bt + (n0 + r) * K + c;
        la[rr] = (char*)As + idx * 16;
        lb[rr] = (char*)Bs + idx * 16;
    }

    f32x4 acc[4][4] = {};

    for (int k0 = 0; k0 < K; k0 += 64) {
#pragma unroll
        for (int rr = 0; rr < 4; ++rr) {
            gl2lds16(ga[rr] + k0, la[rr]);
            gl2lds16(gb[rr] + k0, lb[rr]);
        }
        __syncthreads();
#pragma unroll
        for (int ks = 0; ks < 2; ++ks) {
            s16x8 af[4], bfv[4];
#pragma unroll
            for (int mt = 0; mt < 4; ++mt)
                af[mt] = *(const s16x8*)&As[(wm * 64 + mt * 16 + l16) * 64 + ks * 32 + quad * 8];
#pragma unroll
            for (int nt = 0; nt < 4; ++nt)
                bfv[nt] = *(const s16x8*)&Bs[(wn * 64 + nt * 16 + l16) * 64 + ks * 32 + quad * 8];
#pragma unroll
            for (int mt = 0; mt < 4; ++mt)
#pragma unroll
                for (int nt = 0; nt < 4; ++nt)
                    acc[mt][nt] = __builtin_amdgcn_mfma_f32_16x16x32_bf16(af[mt], bfv[nt], acc[mt][nt], 0, 0, 0);
        }
        __syncthreads();
    }

#pragma unroll
    for (int mt = 0; mt < 4; ++mt)
#pragma unroll
        for (int reg = 0; reg < 4; ++reg) {
            long row = m0 + wm * 64 + mt * 16 + quad * 4 + reg;
#pragma unroll
            for (int nt = 0; nt < 4; ++nt) {
                long col = n0 + wn * 64 + nt * 16 + l16;
                float v = acc[mt][nt][reg];
                if (MODE == 0) {
                    outB[row * N + col] = f2bf(v);
                } else {
                    outF[row * N + col] = resid[row * N + col] + v;
                }
            }
        }
}

// ---------------------------------------------------------------------------
// Fused FFN up-projection: u = bf16( silu(A@B1t^T) * (A@B2t^T) )
// A (M x K) bf16, B1t/B2t (N x K) bf16. 128x128 tile, shared A staging.
// ---------------------------------------------------------------------------
__global__ __launch_bounds__(256, 2) void gemm_ffn(
    const u16* __restrict__ A, const u16* __restrict__ B1t, const u16* __restrict__ B2t,
    const int N, const int K, u16* __restrict__ outB)
{
    __shared__ u16 As[128 * 64];
    __shared__ u16 B1s[128 * 64];
    __shared__ u16 B2s[128 * 64];
    const int tid = threadIdx.x;
    const int lane = tid & 63;
    const int w = tid >> 6;
    const int wm = w >> 1, wn = w & 1;
    const int quad = lane >> 4, l16 = lane & 15;
    const long m0 = (long)blockIdx.x * 128;
    const long n0 = (long)blockIdx.y * 128;

    const u16* ga[4]; const u16* gb1[4]; const u16* gb2[4];
    char* la[4]; char* lb1[4]; char* lb2[4];
#pragma unroll
    for (int rr = 0; rr < 4; ++rr) {
        int idx = rr * 256 + tid;
        int r = idx >> 3, c = (idx & 7) * 8;
        ga[rr]  = A + (m0 + r) * K + c;
        gb1[rr] = B1t + (n0 + r) * K + c;
        gb2[rr] = B2t + (n0 + r) * K + c;
        la[rr]  = (char*)As + idx * 16;
        lb1[rr] = (char*)B1s + idx * 16;
        lb2[rr] = (char*)B2s + idx * 16;
    }

    f32x4 acc1[4][4] = {};
    f32x4 acc2[4][4] = {};

    for (int k0 = 0; k0 < K; k0 += 64) {
#pragma unroll
        for (int rr = 0; rr < 4; ++rr) {
            gl2lds16(ga[rr] + k0, la[rr]);
            gl2lds16(gb1[rr] + k0, lb1[rr]);
            gl2lds16(gb2[rr] + k0, lb2[rr]);
        }
        __syncthreads();
#pragma unroll
        for (int ks = 0; ks < 2; ++ks) {
            s16x8 af[4], b1f[4], b2f[4];
#pragma unroll
            for (int mt = 0; mt < 4; ++mt)
                af[mt] = *(const s16x8*)&As[(wm * 64 + mt * 16 + l16) * 64 + ks * 32 + quad * 8];
#pragma unroll
            for (int nt = 0; nt < 4; ++nt) {
                b1f[nt] = *(const s16x8*)&B1s[(wn * 64 + nt * 16 + l16) * 64 + ks * 32 + quad * 8];
                b2f[nt] = *(const s16x8*)&B2s[(wn * 64 + nt * 16 + l16) * 64 + ks * 32 + quad * 8];
            }
#pragma unroll
            for (int mt = 0; mt < 4; ++mt)
#pragma unroll
                for (int nt = 0; nt < 4; ++nt) {
                    acc1[mt][nt] = __builtin_amdgcn_mfma_f32_16x16x32_bf16(af[mt], b1f[nt], acc1[mt][nt], 0, 0, 0);
                    acc2[mt][nt] = __builtin_amdgcn_mfma_f32_16x16x32_bf16(af[mt], b2f[nt], acc2[mt][nt], 0, 0, 0);
                }
        }
        __syncthreads();
    }

#pragma unroll
    for (int mt = 0; mt < 4; ++mt)
#pragma unroll
        for (int reg = 0; reg < 4; ++reg) {
            long row = m0 + wm * 64 + mt * 16 + quad * 4 + reg;
#pragma unroll
            for (int nt = 0; nt < 4; ++nt) {
                long col = n0 + wn * 64 + nt * 16 + l16;
                float g = acc1[mt][nt][reg];
                float s = g / (1.f + __expf(-g));
                outB[row * N + col] = f2bf(s * acc2[mt][nt][reg]);
            }
        }
}

// ---------------------------------------------------------------------------
// RoPE for q,k: qkv (B*T, 6144) bf16 -> qT/kT [bh][t][d] bf16 (roped)
// grid: (B*T, 32): blockIdx.y = kind*16 + h ; block 128 threads (d)
// ---------------------------------------------------------------------------
__global__ __launch_bounds__(128) void rope_qk(
    const u16* __restrict__ qkv, u16* __restrict__ qT, u16* __restrict__ kT)
{
    const int row = blockIdx.x;          // b*T + t
    const int c = blockIdx.y;
    const int kind = c >> 4, h = c & 15;
    const int d = threadIdx.x;
    const int t = row & 2047, b = row >> 11;
    __shared__ float buf[128];
    float v = bf2f(qkv[(long)row * 6144 + kind * 2048 + h * 128 + d]);
    buf[d] = v;
    __syncthreads();
    const int dh = d & 63;
    float inv_freq = expf((float)dh * -0.14391156831212787f); // ln(10000)/64
    float ang = (float)t * inv_freq;
    float cs = cosf(ang), sn = sinf(ang);
    float x1 = (d < 64) ? v : buf[d - 64];
    float x2 = (d < 64) ? buf[d + 64] : v;
    float outv = (d < 64) ? (x1 * cs - x2 * sn) : (x1 * sn + x2 * cs);
    u16* dst = kind ? kT : qT;
    dst[((long)(b * 16 + h) * 2048 + t) * 128 + d] = f2bf(outv);
}

// ---------------------------------------------------------------------------
// v transpose: qkv v-part (b,t)(h,d) -> vT [bh][d][t]
// grid (32 bh, 32 t-tiles, 2 d-tiles), block 256
// ---------------------------------------------------------------------------
__global__ __launch_bounds__(256) void vtrans(
    const u16* __restrict__ qkv, u16* __restrict__ vT)
{
    const int bh = blockIdx.x;
    const int b = bh >> 4, h = bh & 15;
    const int t0 = blockIdx.y * 64, d0 = blockIdx.z * 64;
    __shared__ u16 tile[64 * 64];
    const int tid = threadIdx.x;
#pragma unroll
    for (int rr = 0; rr < 2; ++rr) {
        int idx = rr * 256 + tid;
        int r = idx >> 3, c = (idx & 7) * 8;
        u16x8 v = *(const u16x8*)&qkv[(long)(b * 2048 + t0 + r) * 6144 + 4096 + h * 128 + d0 + c];
        *(u16x8*)&tile[idx * 8] = v;
    }
    __syncthreads();
#pragma unroll
    for (int rr = 0; rr < 2; ++rr) {
        int idx = rr * 256 + tid;
        int dd = idx >> 3, cc = (idx & 7) * 8;
        u16x8 o;
#pragma unroll
        for (int j = 0; j < 8; ++j) o[j] = tile[(cc + j) * 64 + dd];
        *(u16x8*)&vT[((long)bh * 128 + d0 + dd) * 2048 + t0 + cc] = o;
    }
}

// ---------------------------------------------------------------------------
// Flash attention, causal. grid (T/64 qtiles, B*H), block 256 (4 waves).
// Each wave owns 16 q rows. qT/kT: [bh][t][d], vT: [bh][d][t], out: (b,t,h*128+d)
// ---------------------------------------------------------------------------
__global__ __launch_bounds__(256, 2) void attn_kernel(
    const u16* __restrict__ qT, const u16* __restrict__ kT,
    const u16* __restrict__ vT, u16* __restrict__ outT)
{
    const int T = 2048, D = 128;
    const int qt = blockIdx.x, bh = blockIdx.y;
    const int tid = threadIdx.x, lane = tid & 63, w = tid >> 6;
    const int quad = lane >> 4, l16 = lane & 15;
    const int q0 = qt * 64;
    const int qrow = q0 + w * 16;

    __shared__ u16 Ks[64 * 128];
    __shared__ u16 Vs[128 * 64];
    __shared__ u16 Ps[4][16 * 64];

    s16x8 aq[4];
    const u16* qb = qT + ((long)bh * T + qrow + l16) * D;
#pragma unroll
    for (int kk = 0; kk < 4; ++kk)
        aq[kk] = *(const s16x8*)&qb[kk * 32 + quad * 8];

    f32x4 o[8] = {};
    float mi[4] = {-INFINITY, -INFINITY, -INFINITY, -INFINITY};
    float li[4] = {0.f, 0.f, 0.f, 0.f};

    const u16* kg0 = kT + (long)bh * T * D;
    const u16* vg0 = vT + (long)bh * D * T;

    for (int kt = 0; kt <= qt; ++kt) {
        const int k0 = kt * 64;
        const u16* kg = kg0 + (long)k0 * D;
#pragma unroll
        for (int rr = 0; rr < 4; ++rr) {
            int idx = rr * 256 + tid;
            gl2lds16(kg + idx * 8, (char*)Ks + idx * 16);
            int dd = idx >> 3, cc = (idx & 7) * 8;
            gl2lds16(vg0 + (long)dd * T + k0 + cc, (char*)Vs + idx * 16);
        }
        __syncthreads();

        // S = Q K^T  (16 q rows x 64 keys per wave)
        f32x4 sf[4] = {};
#pragma unroll
        for (int kk = 0; kk < 4; ++kk) {
#pragma unroll
            for (int nt = 0; nt < 4; ++nt) {
                s16x8 kb = *(const s16x8*)&Ks[(nt * 16 + l16) * 128 + kk * 32 + quad * 8];
                sf[nt] = __builtin_amdgcn_mfma_f32_16x16x32_bf16(aq[kk], kb, sf[nt], 0, 0, 0);
            }
        }

        float S[4][4];
#pragma unroll
        for (int nt = 0; nt < 4; ++nt) {
            int col = k0 + nt * 16 + l16;
#pragma unroll
            for (int reg = 0; reg < 4; ++reg) {
                int row = qrow + quad * 4 + reg;
                float s = sf[nt][reg] * 0.08838834764831845f;
                S[nt][reg] = (col <= row) ? s : -INFINITY;
            }
        }
        float rm[4];
#pragma unroll
        for (int reg = 0; reg < 4; ++reg)
            rm[reg] = fmaxf(fmaxf(S[0][reg], S[1][reg]), fmaxf(S[2][reg], S[3][reg]));
#pragma unroll
        for (int m = 1; m < 16; m <<= 1)
#pragma unroll
            for (int reg = 0; reg < 4; ++reg)
                rm[reg] = fmaxf(rm[reg], __shfl_xor(rm[reg], m));

        float alpha[4], rs[4];
#pragma unroll
        for (int reg = 0; reg < 4; ++reg) {
            float mn = fmaxf(mi[reg], rm[reg]);
            alpha[reg] = __expf(mi[reg] - mn);
            mi[reg] = mn;
            rs[reg] = 0.f;
        }
#pragma unroll
        for (int nt = 0; nt < 4; ++nt)
#pragma unroll
            for (int reg = 0; reg < 4; ++reg) {
                float p = __expf(S[nt][reg] - mi[reg]);
                S[nt][reg] = p;
                rs[reg] += p;
            }
#pragma unroll
        for (int m = 1; m < 16; m <<= 1)
#pragma unroll
            for (int reg = 0; reg < 4; ++reg)
                rs[reg] += __shfl_xor(rs[reg], m);
#pragma unroll
        for (int reg = 0; reg < 4; ++reg)
            li[reg] = li[reg] * alpha[reg] + rs[reg];
#pragma unroll
        for (int dt = 0; dt < 8; ++dt)
#pragma unroll
            for (int reg = 0; reg < 4; ++reg)
                o[dt][reg] *= alpha[reg];

        // P -> LDS (C-layout -> A-operand layout round trip)
#pragma unroll
        for (int nt = 0; nt < 4; ++nt)
#pragma unroll
            for (int reg = 0; reg < 4; ++reg)
                Ps[w][(quad * 4 + reg) * 64 + nt * 16 + l16] = f2bf(S[nt][reg]);
        __syncthreads();

        // O += P V
#pragma unroll
        for (int ks = 0; ks < 2; ++ks) {
            s16x8 pa = *(const s16x8*)&Ps[w][l16 * 64 + ks * 32 + quad * 8];
#pragma unroll
            for (int dt = 0; dt < 8; ++dt) {
                s16x8 vb = *(const s16x8*)&Vs[(dt * 16 + l16) * 64 + ks * 32 + quad * 8];
                o[dt] = __builtin_amdgcn_mfma_f32_16x16x32_bf16(pa, vb, o[dt], 0, 0, 0);
            }
        }
        __syncthreads();
    }

    const int b = bh >> 4, h = bh & 15;
#pragma unroll
    for (int reg = 0; reg < 4; ++reg) {
        float inv = 1.f / li[reg];
        int t = qrow + quad * 4 + reg;
        u16* orow = outT + ((long)(b * T + t)) * 2048 + h * 128;
#pragma unroll
        for (int dt = 0; dt < 8; ++dt)
            orow[dt * 16 + l16] = f2bf(o[dt][reg] * inv);
    }
}

// ---------------------------------------------------------------------------
// Workspace layout (188 MiB total, unions by live-range):
//   Z     24 MiB : wqkv_t  -> w3_t (after qkv GEMM)
//   wproj  8 MiB
//   w1_t  22 MiB
//   w2_t  22 MiB
//   C     16 MiB : h (norm1) -> attn_out -> h2 (norm2)
//   D     48 MiB : qkv -> u (FFN intermediate, 46.1 MiB)
//   E     48 MiB : qT(16)+kT(16)+vT(16) -> x2 (fp32 residual, 32 MiB)
// ---------------------------------------------------------------------------
extern "C" void kernel_launch(void* const* d_in, const int* in_sizes, int n_in,
                              void* d_out, int out_size, void* d_ws, size_t ws_size,
                              hipStream_t stream) {
    const float* x      = (const float*)d_in[0];
    const float* wn1    = (const float*)d_in[1];
    const float* w_qkv  = (const float*)d_in[2];
    const float* w_proj = (const float*)d_in[3];
    const float* wn2    = (const float*)d_in[4];
    const float* w1     = (const float*)d_in[5];
    const float* w2     = (const float*)d_in[6];
    const float* w3     = (const float*)d_in[7];
    float* out = (float*)d_out;

    char* p = (char*)d_ws;
    u16* Z       = (u16*)p; p += (size_t)6144 * 2048 * 2;   // wqkv_t / w3_t
    u16* wproj_t = (u16*)p; p += (size_t)2048 * 2048 * 2;
    u16* w1_t    = (u16*)p; p += (size_t)5632 * 2048 * 2;
    u16* w2_t    = (u16*)p; p += (size_t)5632 * 2048 * 2;
    u16* C       = (u16*)p; p += (size_t)4096 * 2048 * 2;   // h / attno / h2
    u16* D       = (u16*)p; p += (size_t)4096 * 6144 * 2;   // qkv / u
    u16* E       = (u16*)p; p += (size_t)3 * 32 * 2048 * 128 * 2; // qT,kT,vT / x2

    u16* wqkv_t = Z;
    u16* w3_t   = Z;
    u16* qT = E;
    u16* kT = E + (size_t)32 * 2048 * 128;
    u16* vT = E + (size_t)2 * 32 * 2048 * 128;
    float* x2 = (float*)E;
    u16* uu = D;

    // weight transpose-casts (w3 deferred until wqkv_t is dead)
    tcast<<<dim3(64, 192), 256, 0, stream>>>(w_qkv, wqkv_t, 2048, 6144);
    tcast<<<dim3(64, 64), 256, 0, stream>>>(w_proj, wproj_t, 2048, 2048);
    tcast<<<dim3(64, 176), 256, 0, stream>>>(w1, w1_t, 2048, 5632);
    tcast<<<dim3(64, 176), 256, 0, stream>>>(w2, w2_t, 2048, 5632);

    // norm1 + qkv
    rmsnorm_cast<<<4096, 256, 0, stream>>>(x, wn1, C);
    gemm128<0><<<dim3(32, 48), 256, 0, stream>>>(C, wqkv_t, 6144, 2048,
                                                 nullptr, D, nullptr);
    // rope + head layout
    rope_qk<<<dim3(4096, 32), 128, 0, stream>>>(D, qT, kT);
    vtrans<<<dim3(32, 32, 2), 256, 0, stream>>>(D, vT);

    // w3 transpose now that wqkv_t (Z) is dead
    tcast<<<dim3(176, 64), 256, 0, stream>>>(w3, w3_t, 5632, 2048);

    // attention -> C
    attn_kernel<<<dim3(32, 32), 256, 0, stream>>>(qT, kT, vT, C);

    // proj + residual -> x2 (fp32, overwrites E after attn consumed q/k/v)
    gemm128<1><<<dim3(32, 16), 256, 0, stream>>>(C, wproj_t, 2048, 2048,
                                                 x2, nullptr, x);
    // norm2 -> C
    rmsnorm_cast<<<4096, 256, 0, stream>>>(x2, wn2, C);
    // fused FFN up: u = silu(h2@w1) * (h2@w2) -> D
    gemm_ffn<<<dim3(32, 44), 256, 0, stream>>>(C, w1_t, w2_t, 5632, 2048, uu);
    // down-proj + residual -> out
    gemm128<1><<<dim3(32, 16), 256, 0, stream>>>(uu, w3_t, 2048, 5632,
                                                 out, nullptr, x2);
}

// Round 3
// 879.427 us; speedup vs baseline: 1.2616x; 1.2616x over previous
//
#include <hip/hip_runtime.h>

typedef short s16x8 __attribute__((ext_vector_type(8)));
typedef unsigned short u16;
typedef u16 u16x8 __attribute__((ext_vector_type(8)));
typedef u16 u16x4 __attribute__((ext_vector_type(4)));
typedef float f32x4 __attribute__((ext_vector_type(4)));

#define DEVINL __device__ __forceinline__

DEVINL u16 f2bf(float f) {
    unsigned u = __float_as_uint(f);
    u += 0x7FFFu + ((u >> 16) & 1u);
    return (u16)(u >> 16);
}
DEVINL float bf2f(u16 h) { return __uint_as_float((unsigned)h << 16); }

DEVINL void gl2lds16(const void* g, void* l) {
    __builtin_amdgcn_global_load_lds((const __attribute__((address_space(1))) void*)g,
                                     (__attribute__((address_space(3))) void*)l, 16, 0, 0);
}

// ---------------------------------------------------------------------------
// Transpose-cast: src (K,N) fp32 row-major -> dst (N,K) bf16 row-major
// ---------------------------------------------------------------------------
__global__ __launch_bounds__(256) void tcast(
    const float* __restrict__ src, u16* __restrict__ dst, const int K, const int N)
{
    __shared__ float tile[32][33];
    const long k0 = (long)blockIdx.x * 32;
    const long n0 = (long)blockIdx.y * 32;
    const int tid = threadIdx.x;
    const int r = tid >> 3, c4 = (tid & 7) * 4;
    float4 v = *(const float4*)&src[(k0 + r) * N + n0 + c4];
    tile[r][c4] = v.x; tile[r][c4 + 1] = v.y; tile[r][c4 + 2] = v.z; tile[r][c4 + 3] = v.w;
    __syncthreads();
    u16x4 ov;
    ov[0] = f2bf(tile[c4][r]);     ov[1] = f2bf(tile[c4 + 1][r]);
    ov[2] = f2bf(tile[c4 + 2][r]); ov[3] = f2bf(tile[c4 + 3][r]);
    *(u16x4*)&dst[(n0 + r) * K + k0 + c4] = ov;
}

// ---------------------------------------------------------------------------
// RMSNorm (C=2048) fp32 -> bf16
// ---------------------------------------------------------------------------
__global__ __launch_bounds__(256) void rmsnorm_cast(
    const float* __restrict__ x, const float* __restrict__ wn, u16* __restrict__ out)
{
    const int C = 2048;
    const long row = blockIdx.x;
    const int tid = threadIdx.x;
    const float4* xr = (const float4*)(x + row * C);
    float4 a = xr[tid * 2], b = xr[tid * 2 + 1];
    float ss = a.x*a.x + a.y*a.y + a.z*a.z + a.w*a.w
             + b.x*b.x + b.y*b.y + b.z*b.z + b.w*b.w;
#pragma unroll
    for (int m = 1; m < 64; m <<= 1) ss += __shfl_xor(ss, m);
    __shared__ float red[4];
    if ((tid & 63) == 0) red[tid >> 6] = ss;
    __syncthreads();
    float scale = rsqrtf((red[0] + red[1] + red[2] + red[3]) * (1.f / 2048.f) + 1e-6f);
    const float4* wr = (const float4*)wn;
    float4 wa = wr[tid * 2], wb = wr[tid * 2 + 1];
    u16x8 o;
    o[0] = f2bf(a.x * scale * wa.x); o[1] = f2bf(a.y * scale * wa.y);
    o[2] = f2bf(a.z * scale * wa.z); o[3] = f2bf(a.w * scale * wa.w);
    o[4] = f2bf(b.x * scale * wb.x); o[5] = f2bf(b.y * scale * wb.y);
    o[6] = f2bf(b.z * scale * wb.z); o[7] = f2bf(b.w * scale * wb.w);
    *(u16x8*)&out[row * C + tid * 8] = o;
}

// ---------------------------------------------------------------------------
// GEMM: A (M x K) bf16 row-major, Bt (N x K) bf16 row-major, 128x128 tile.
// LDS tiles XOR-swizzled: chunk j of row r stored at slot j^(r&7).
// MODE 0: outB = bf16(acc)   MODE 1: outF = resid + acc (fp32)
// ---------------------------------------------------------------------------
template <int MODE>
__global__ __launch_bounds__(256, 2) void gemm128(
    const u16* __restrict__ A, const u16* __restrict__ Bt,
    const int N, const int K,
    float* __restrict__ outF, u16* __restrict__ outB,
    const float* __restrict__ resid)
{
    __shared__ u16 As[128 * 64];
    __shared__ u16 Bs[128 * 64];
    const int tid = threadIdx.x;
    const int lane = tid & 63;
    const int w = tid >> 6;
    const int wm = w >> 1, wn = w & 1;
    const int quad = lane >> 4, l16 = lane & 15;
    const long m0 = (long)blockIdx.x * 128;
    const long n0 = (long)blockIdx.y * 128;

    const u16* ga[4]; const u16* gb[4]; char* la[4]; char* lb[4];
#pragma unroll
    for (int rr = 0; rr < 4; ++rr) {
        int idx = rr * 256 + tid;
        int r = idx >> 3, j = idx & 7;
        int c = (j ^ (r & 7)) * 8;          // XOR source-swizzle
        ga[rr] = A + (m0 + r) * K + c;
        gb[rr] = Bt + (n0 + r) * K + c;
        la[rr] = (char*)As + idx * 16;
        lb[rr] = (char*)Bs + idx * 16;
    }

    f32x4 acc[4][4] = {};

    for (int k0 = 0; k0 < K; k0 += 64) {
#pragma unroll
        for (int rr = 0; rr < 4; ++rr) {
            gl2lds16(ga[rr] + k0, la[rr]);
            gl2lds16(gb[rr] + k0, lb[rr]);
        }
        __syncthreads();
#pragma unroll
        for (int ks = 0; ks < 2; ++ks) {
            s16x8 af[4], bfv[4];
#pragma unroll
            for (int mt = 0; mt < 4; ++mt)
                af[mt] = *(const s16x8*)&As[(wm * 64 + mt * 16 + l16) * 64 +
                                            ((ks * 4 + quad) ^ (l16 & 7)) * 8];
#pragma unroll
            for (int nt = 0; nt < 4; ++nt)
                bfv[nt] = *(const s16x8*)&Bs[(wn * 64 + nt * 16 + l16) * 64 +
                                             ((ks * 4 + quad) ^ (l16 & 7)) * 8];
#pragma unroll
            for (int mt = 0; mt < 4; ++mt)
#pragma unroll
                for (int nt = 0; nt < 4; ++nt)
                    acc[mt][nt] = __builtin_amdgcn_mfma_f32_16x16x32_bf16(af[mt], bfv[nt], acc[mt][nt], 0, 0, 0);
        }
        __syncthreads();
    }

#pragma unroll
    for (int mt = 0; mt < 4; ++mt)
#pragma unroll
        for (int reg = 0; reg < 4; ++reg) {
            long row = m0 + wm * 64 + mt * 16 + quad * 4 + reg;
#pragma unroll
            for (int nt = 0; nt < 4; ++nt) {
                long col = n0 + wn * 64 + nt * 16 + l16;
                float v = acc[mt][nt][reg];
                if (MODE == 0) {
                    outB[row * N + col] = f2bf(v);
                } else {
                    outF[row * N + col] = resid[row * N + col] + v;
                }
            }
        }
}

// ---------------------------------------------------------------------------
// Fused FFN up-projection: u = bf16( silu(A@B1t^T) * (A@B2t^T) )
// ---------------------------------------------------------------------------
__global__ __launch_bounds__(256, 2) void gemm_ffn(
    const u16* __restrict__ A, const u16* __restrict__ B1t, const u16* __restrict__ B2t,
    const int N, const int K, u16* __restrict__ outB)
{
    __shared__ u16 As[128 * 64];
    __shared__ u16 B1s[128 * 64];
    __shared__ u16 B2s[128 * 64];
    const int tid = threadIdx.x;
    const int lane = tid & 63;
    const int w = tid >> 6;
    const int wm = w >> 1, wn = w & 1;
    const int quad = lane >> 4, l16 = lane & 15;
    const long m0 = (long)blockIdx.x * 128;
    const long n0 = (long)blockIdx.y * 128;

    const u16* ga[4]; const u16* gb1[4]; const u16* gb2[4];
    char* la[4]; char* lb1[4]; char* lb2[4];
#pragma unroll
    for (int rr = 0; rr < 4; ++rr) {
        int idx = rr * 256 + tid;
        int r = idx >> 3, j = idx & 7;
        int c = (j ^ (r & 7)) * 8;
        ga[rr]  = A + (m0 + r) * K + c;
        gb1[rr] = B1t + (n0 + r) * K + c;
        gb2[rr] = B2t + (n0 + r) * K + c;
        la[rr]  = (char*)As + idx * 16;
        lb1[rr] = (char*)B1s + idx * 16;
        lb2[rr] = (char*)B2s + idx * 16;
    }

    f32x4 acc1[4][4] = {};
    f32x4 acc2[4][4] = {};

    for (int k0 = 0; k0 < K; k0 += 64) {
#pragma unroll
        for (int rr = 0; rr < 4; ++rr) {
            gl2lds16(ga[rr] + k0, la[rr]);
            gl2lds16(gb1[rr] + k0, lb1[rr]);
            gl2lds16(gb2[rr] + k0, lb2[rr]);
        }
        __syncthreads();
#pragma unroll
        for (int ks = 0; ks < 2; ++ks) {
            s16x8 af[4], b1f[4], b2f[4];
#pragma unroll
            for (int mt = 0; mt < 4; ++mt)
                af[mt] = *(const s16x8*)&As[(wm * 64 + mt * 16 + l16) * 64 +
                                            ((ks * 4 + quad) ^ (l16 & 7)) * 8];
#pragma unroll
            for (int nt = 0; nt < 4; ++nt) {
                b1f[nt] = *(const s16x8*)&B1s[(wn * 64 + nt * 16 + l16) * 64 +
                                              ((ks * 4 + quad) ^ (l16 & 7)) * 8];
                b2f[nt] = *(const s16x8*)&B2s[(wn * 64 + nt * 16 + l16) * 64 +
                                              ((ks * 4 + quad) ^ (l16 & 7)) * 8];
            }
#pragma unroll
            for (int mt = 0; mt < 4; ++mt)
#pragma unroll
                for (int nt = 0; nt < 4; ++nt) {
                    acc1[mt][nt] = __builtin_amdgcn_mfma_f32_16x16x32_bf16(af[mt], b1f[nt], acc1[mt][nt], 0, 0, 0);
                    acc2[mt][nt] = __builtin_amdgcn_mfma_f32_16x16x32_bf16(af[mt], b2f[nt], acc2[mt][nt], 0, 0, 0);
                }
        }
        __syncthreads();
    }

#pragma unroll
    for (int mt = 0; mt < 4; ++mt)
#pragma unroll
        for (int reg = 0; reg < 4; ++reg) {
            long row = m0 + wm * 64 + mt * 16 + quad * 4 + reg;
#pragma unroll
            for (int nt = 0; nt < 4; ++nt) {
                long col = n0 + wn * 64 + nt * 16 + l16;
                float g = acc1[mt][nt][reg];
                float s = g / (1.f + __expf(-g));
                outB[row * N + col] = f2bf(s * acc2[mt][nt][reg]);
            }
        }
}

// ---------------------------------------------------------------------------
// RoPE, vectorized: one block per (b,t) row; q scaled by 1/sqrt(D).
// qkv (B*T, 6144) bf16 -> qT/kT [bh][t][d]
// ---------------------------------------------------------------------------
__global__ __launch_bounds__(256) void rope_qk(
    const u16* __restrict__ qkv, u16* __restrict__ qT, u16* __restrict__ kT)
{
    const int row = blockIdx.x;
    const int t = row & 2047, b = row >> 11;
    const int tid = threadIdx.x;
    __shared__ u16 buf[4096];
    const u16* src = qkv + (long)row * 6144;
    u16x8 aa = *(const u16x8*)&src[tid * 8];
    u16x8 kk = *(const u16x8*)&src[2048 + tid * 8];
    *(u16x8*)&buf[tid * 8] = aa;
    *(u16x8*)&buf[2048 + tid * 8] = kk;
    __syncthreads();
    const int c = tid * 8;
    const int h = c >> 7, dh = c & 127;
    const bool first = dh < 64;
    const int pc = first ? (c + 64) : (c - 64);
    float cs[8], sn[8];
#pragma unroll
    for (int j = 0; j < 8; ++j) {
        float inv = __expf(-(float)((dh & 63) + j) * 0.14391156831212787f); // ln(1e4)/64
        float ang = (float)t * inv;
        cs[j] = cosf(ang); sn[j] = sinf(ang);
    }
    const long obase = ((long)(b * 16 + h) * 2048 + t) * 128 + dh;
#pragma unroll
    for (int part = 0; part < 2; ++part) {
        const int base = part * 2048;
        u16x8 mine = *(const u16x8*)&buf[base + c];
        u16x8 oth  = *(const u16x8*)&buf[base + pc];
        const float qs = part ? 1.f : 0.08838834764831845f;
        u16x8 o;
#pragma unroll
        for (int j = 0; j < 8; ++j) {
            float xv = bf2f(mine[j]), yv = bf2f(oth[j]);
            float ov = first ? (xv * cs[j] - yv * sn[j]) : (yv * sn[j] + xv * cs[j]);
            o[j] = f2bf(ov * qs);
        }
        u16* dst = part ? kT : qT;
        *(u16x8*)&dst[obase] = o;
    }
}

// ---------------------------------------------------------------------------
// v transpose: qkv v-part (b,t)(h,d) -> vT [bh][d][t].  LDS stride 65 (odd).
// ---------------------------------------------------------------------------
__global__ __launch_bounds__(256) void vtrans(
    const u16* __restrict__ qkv, u16* __restrict__ vT)
{
    const int bh = blockIdx.x;
    const int b = bh >> 4, h = bh & 15;
    const int t0 = blockIdx.y * 64, d0 = blockIdx.z * 64;
    __shared__ u16 tile[64 * 65];
    const int tid = threadIdx.x;
#pragma unroll
    for (int rr = 0; rr < 2; ++rr) {
        int idx = rr * 256 + tid;
        int r = idx >> 3, c = (idx & 7) * 8;
        u16x8 v = *(const u16x8*)&qkv[(long)(b * 2048 + t0 + r) * 6144 + 4096 + h * 128 + d0 + c];
#pragma unroll
        for (int j = 0; j < 8; ++j) tile[r * 65 + c + j] = v[j];
    }
    __syncthreads();
#pragma unroll
    for (int rr = 0; rr < 2; ++rr) {
        int idx = rr * 256 + tid;
        int dd = idx >> 3, cc = (idx & 7) * 8;
        u16x8 o;
#pragma unroll
        for (int j = 0; j < 8; ++j) o[j] = tile[(cc + j) * 65 + dd];
        *(u16x8*)&vT[((long)bh * 128 + d0 + dd) * 2048 + t0 + cc] = o;
    }
}

// ---------------------------------------------------------------------------
// Flash attention, causal. grid (32 qtiles reversed, 32 bh), 256 thr (4 waves).
// Each wave owns 16 q rows. Double-buffered K/V, 1 barrier/iteration,
// XOR-swizzled LDS. q pre-scaled by 1/sqrt(D).
// ---------------------------------------------------------------------------
__global__ __launch_bounds__(256, 2) void attn_kernel(
    const u16* __restrict__ qT, const u16* __restrict__ kT,
    const u16* __restrict__ vT, u16* __restrict__ outT)
{
    const int T = 2048, D = 128;
    const int qt = gridDim.x - 1 - blockIdx.x;   // heavy q-tiles dispatch first
    const int bh = blockIdx.y;
    const int tid = threadIdx.x, lane = tid & 63, w = tid >> 6;
    const int quad = lane >> 4, l16 = lane & 15;
    const int qrow = qt * 64 + w * 16;

    __shared__ u16 Ks[2][64 * 128];
    __shared__ u16 Vs[2][128 * 64];
    __shared__ u16 Ps[4][16 * 64];

    s16x8 aq[4];
    const u16* qb = qT + ((long)bh * T + qrow + l16) * D;
#pragma unroll
    for (int kk = 0; kk < 4; ++kk)
        aq[kk] = *(const s16x8*)&qb[kk * 32 + quad * 8];

    f32x4 o[8] = {};
    float mi[4] = {-INFINITY, -INFINITY, -INFINITY, -INFINITY};
    float li[4] = {0.f, 0.f, 0.f, 0.f};

    const u16* kg0 = kT + (long)bh * T * D;
    const u16* vg0 = vT + (long)bh * D * T;

    auto stage = [&](int kt, int b) {
        const int k0 = kt * 64;
#pragma unroll
        for (int rr = 0; rr < 4; ++rr) {
            int idx = rr * 256 + tid;
            int kr = idx >> 4, kj = idx & 15;
            gl2lds16(kg0 + (long)(k0 + kr) * D + ((kj ^ (kr & 15)) * 8),
                     (char*)Ks[b] + idx * 16);
            int vr = idx >> 3, vj = idx & 7;
            gl2lds16(vg0 + (long)vr * T + k0 + ((vj ^ (vr & 7)) * 8),
                     (char*)Vs[b] + idx * 16);
        }
    };

    stage(0, 0);

    for (int kt = 0; kt <= qt; ++kt) {
        __syncthreads();                 // buf[kt&1] ready (loads had 1 full iter)
        if (kt < qt) stage(kt + 1, (kt + 1) & 1);
        const u16* ks_ = Ks[kt & 1];
        const u16* vs_ = Vs[kt & 1];
        const int k0 = kt * 64;

        // S = Q K^T
        f32x4 sf[4] = {};
#pragma unroll
        for (int kk = 0; kk < 4; ++kk) {
#pragma unroll
            for (int nt = 0; nt < 4; ++nt) {
                s16x8 kb = *(const s16x8*)&ks_[(nt * 16 + l16) * 128 +
                                               ((kk * 4 + quad) ^ (l16 & 15)) * 8];
                sf[nt] = __builtin_amdgcn_mfma_f32_16x16x32_bf16(aq[kk], kb, sf[nt], 0, 0, 0);
            }
        }

        float S[4][4];
        if (kt == qt) {   // diagonal tile: causal mask
#pragma unroll
            for (int nt = 0; nt < 4; ++nt) {
                int col = k0 + nt * 16 + l16;
#pragma unroll
                for (int reg = 0; reg < 4; ++reg) {
                    int row = qrow + quad * 4 + reg;
                    S[nt][reg] = (col <= row) ? sf[nt][reg] : -INFINITY;
                }
            }
        } else {
#pragma unroll
            for (int nt = 0; nt < 4; ++nt)
#pragma unroll
                for (int reg = 0; reg < 4; ++reg)
                    S[nt][reg] = sf[nt][reg];
        }

        float rm[4];
#pragma unroll
        for (int reg = 0; reg < 4; ++reg)
            rm[reg] = fmaxf(fmaxf(S[0][reg], S[1][reg]), fmaxf(S[2][reg], S[3][reg]));
#pragma unroll
        for (int m = 1; m < 16; m <<= 1)
#pragma unroll
            for (int reg = 0; reg < 4; ++reg)
                rm[reg] = fmaxf(rm[reg], __shfl_xor(rm[reg], m));

        float alpha[4], rs[4];
#pragma unroll
        for (int reg = 0; reg < 4; ++reg) {
            float mn = fmaxf(mi[reg], rm[reg]);
            alpha[reg] = __expf(mi[reg] - mn);
            mi[reg] = mn;
            rs[reg] = 0.f;
        }
#pragma unroll
        for (int nt = 0; nt < 4; ++nt)
#pragma unroll
            for (int reg = 0; reg < 4; ++reg) {
                float p = __expf(S[nt][reg] - mi[reg]);
                S[nt][reg] = p;
                rs[reg] += p;
            }
#pragma unroll
        for (int m = 1; m < 16; m <<= 1)
#pragma unroll
            for (int reg = 0; reg < 4; ++reg)
                rs[reg] += __shfl_xor(rs[reg], m);
#pragma unroll
        for (int reg = 0; reg < 4; ++reg)
            li[reg] = li[reg] * alpha[reg] + rs[reg];
#pragma unroll
        for (int dt = 0; dt < 8; ++dt)
#pragma unroll
            for (int reg = 0; reg < 4; ++reg)
                o[dt][reg] *= alpha[reg];

        // P -> LDS, wave-private region (no barrier needed), XOR-swizzled
#pragma unroll
        for (int nt = 0; nt < 4; ++nt)
#pragma unroll
            for (int reg = 0; reg < 4; ++reg) {
                int prow = quad * 4 + reg;
                int pcol = nt * 16 + l16;
                Ps[w][prow * 64 + (((pcol >> 3) ^ (prow & 7)) * 8) + (pcol & 7)]
                    = f2bf(S[nt][reg]);
            }

        // O += P V   (Ps read: row l16, chunk ks*4+quad, swizzled)
#pragma unroll
        for (int ks = 0; ks < 2; ++ks) {
            s16x8 pa = *(const s16x8*)&Ps[w][l16 * 64 +
                                             ((ks * 4 + quad) ^ (l16 & 7)) * 8];
#pragma unroll
            for (int dt = 0; dt < 8; ++dt) {
                s16x8 vb = *(const s16x8*)&vs_[(dt * 16 + l16) * 64 +
                                               ((ks * 4 + quad) ^ (l16 & 7)) * 8];
                o[dt] = __builtin_amdgcn_mfma_f32_16x16x32_bf16(pa, vb, o[dt], 0, 0, 0);
            }
        }
    }

    const int b = bh >> 4, h = bh & 15;
#pragma unroll
    for (int reg = 0; reg < 4; ++reg) {
        float inv = 1.f / li[reg];
        int t = qrow + quad * 4 + reg;
        u16* orow = outT + ((long)(b * T + t)) * 2048 + h * 128;
#pragma unroll
        for (int dt = 0; dt < 8; ++dt)
            orow[dt * 16 + l16] = f2bf(o[dt][reg] * inv);
    }
}

// ---------------------------------------------------------------------------
// Workspace layout (188 MiB total, unions by live-range):
//   Z 24 MiB: wqkv_t -> w3_t | wproj 8 | w1_t 22 | w2_t 22
//   C 16 MiB: h -> attn_out -> h2 | D 48 MiB: qkv -> u | E 48 MiB: q/k/vT -> x2
// ---------------------------------------------------------------------------
extern "C" void kernel_launch(void* const* d_in, const int* in_sizes, int n_in,
                              void* d_out, int out_size, void* d_ws, size_t ws_size,
                              hipStream_t stream) {
    const float* x      = (const float*)d_in[0];
    const float* wn1    = (const float*)d_in[1];
    const float* w_qkv  = (const float*)d_in[2];
    const float* w_proj = (const float*)d_in[3];
    const float* wn2    = (const float*)d_in[4];
    const float* w1     = (const float*)d_in[5];
    const float* w2     = (const float*)d_in[6];
    const float* w3     = (const float*)d_in[7];
    float* out = (float*)d_out;

    char* p = (char*)d_ws;
    u16* Z       = (u16*)p; p += (size_t)6144 * 2048 * 2;
    u16* wproj_t = (u16*)p; p += (size_t)2048 * 2048 * 2;
    u16* w1_t    = (u16*)p; p += (size_t)5632 * 2048 * 2;
    u16* w2_t    = (u16*)p; p += (size_t)5632 * 2048 * 2;
    u16* C       = (u16*)p; p += (size_t)4096 * 2048 * 2;
    u16* D       = (u16*)p; p += (size_t)4096 * 6144 * 2;
    u16* E       = (u16*)p; p += (size_t)3 * 32 * 2048 * 128 * 2;

    u16* wqkv_t = Z;
    u16* w3_t   = Z;
    u16* qT = E;
    u16* kT = E + (size_t)32 * 2048 * 128;
    u16* vT = E + (size_t)2 * 32 * 2048 * 128;
    float* x2 = (float*)E;
    u16* uu = D;

    tcast<<<dim3(64, 192), 256, 0, stream>>>(w_qkv, wqkv_t, 2048, 6144);
    tcast<<<dim3(64, 64), 256, 0, stream>>>(w_proj, wproj_t, 2048, 2048);
    tcast<<<dim3(64, 176), 256, 0, stream>>>(w1, w1_t, 2048, 5632);
    tcast<<<dim3(64, 176), 256, 0, stream>>>(w2, w2_t, 2048, 5632);

    rmsnorm_cast<<<4096, 256, 0, stream>>>(x, wn1, C);
    gemm128<0><<<dim3(32, 48), 256, 0, stream>>>(C, wqkv_t, 6144, 2048,
                                                 nullptr, D, nullptr);
    rope_qk<<<4096, 256, 0, stream>>>(D, qT, kT);
    vtrans<<<dim3(32, 32, 2), 256, 0, stream>>>(D, vT);

    tcast<<<dim3(176, 64), 256, 0, stream>>>(w3, w3_t, 5632, 2048);

    attn_kernel<<<dim3(32, 32), 256, 0, stream>>>(qT, kT, vT, C);

    gemm128<1><<<dim3(32, 16), 256, 0, stream>>>(C, wproj_t, 2048, 2048,
                                                 x2, nullptr, x);
    rmsnorm_cast<<<4096, 256, 0, stream>>>(x2, wn2, C);
    gemm_ffn<<<dim3(32, 44), 256, 0, stream>>>(C, w1_t, w2_t, 5632, 2048, uu);
    gemm128<1><<<dim3(32, 16), 256, 0, stream>>>(uu, w3_t, 2048, 5632,
                                                 out, nullptr, x2);
}